// Round 4
// baseline (2067.941 us; speedup 1.0000x reference)
//
#include <hip/hip_runtime.h>
#include <cstdint>
#include <cstddef>

// Problem constants
#define BB   64     // batch
#define TT   512    // time steps
#define HH   256    // hidden
#define G4   1024   // 4*H
#define NL   8      // layers
#define NW   32     // workgroups per layer (hidden-unit slices)
#define HPW  8      // hidden units per WG
#define NR   32     // gate rows per WG (4 gates * HPW)

typedef _Float16 half8 __attribute__((ext_vector_type(8)));
typedef float   floatx4 __attribute__((ext_vector_type(4)));

__device__ __forceinline__ float sigm(float v)   { return 1.0f / (1.0f + __expf(-v)); }
__device__ __forceinline__ float tanh_f(float v) { return 1.0f - 2.0f / (__expf(2.0f * v) + 1.0f); }

// ---- coherent access helpers (bypass L1+L2, served at IF$ coherence point) ----
__device__ __forceinline__ void gload8_x(half8& d, const _Float16* p) {
  asm volatile("global_load_dwordx4 %0, %1, off sc0 sc1" : "=v"(d) : "v"(p) : "memory");
}
__device__ __forceinline__ void stdword_x(int* p, int v) {
  asm volatile("global_store_dword %0, %1, off sc0 sc1" :: "v"(p), "v"(v) : "memory");
}
__device__ __forceinline__ void wait_vm0() {
  asm volatile("s_waitcnt vmcnt(0)" ::: "memory");
}
__device__ __forceinline__ int ldflag_x(const int* p) {
  int v; asm volatile("global_load_dword %0, %1, off sc0 sc1" : "=v"(v) : "v"(p) : "memory");
  wait_vm0(); return v;
}

// hseq layout per layer: [t][kblk=H/8=32][b=64][8] fp16 (MFMA A-fragment friendly)
#define TSTRIDE ((size_t)32 * BB * 8)         // 16384 elems per t
#define LSTRIDE ((size_t)TT * TSTRIDE)        // 8,388,608 elems per layer (16 MB)

// ---------------------------------------------------------------------------
// xg0 table: table[v][n] = sum_e emb[v][e] * Wih0[n][e]   (biases NOT included)
__global__ void build_xg0(const float* __restrict__ emb, const float* __restrict__ Wih0,
                          float* __restrict__ table) {
  int i = blockIdx.x * 256 + threadIdx.x;
  if (i >= 23 * G4) return;
  int v = i >> 10, n = i & (G4 - 1);
  float a = 0.f;
#pragma unroll
  for (int e = 0; e < 16; ++e) a += emb[v * 16 + e] * Wih0[n * 16 + e];
  table[i] = a;
}

// ---------------------------------------------------------------------------
// Persistent pipelined LSTM. grid = 256 blocks (NL layers x NW slices), 256 thr.
// vs round 2: (1) both producer flags polled in PARALLEL by different waves,
// then all 16 A+B loads issued together under one vmcnt(0) -> the two IF$
// round trips overlap instead of serializing; (2) per-slice monotonic counters
// (cnt[l][w] = steps published) replace the 32-way contended atomicAdd;
// (3) h published directly from registers as packed fp16x2 dwords (no LDS stage).
__global__ __launch_bounds__(256, 1) void lstm_pipeline(
    const int*   __restrict__ x,         // [B][T]
    const float* __restrict__ Wih_rest,  // [7][1024][256]
    const float* __restrict__ Whh,       // [8][1024][256]
    const float* __restrict__ bih,       // [8][1024]
    const float* __restrict__ bhh,       // [8][1024]
    const float* __restrict__ xg0t,      // [23][1024]
    _Float16* __restrict__ hseq,         // NL * LSTRIDE fp16
    int* __restrict__ cnt)               // [NL][NW] monotonic step counters
{
  const int l   = blockIdx.x & 7;
  const int w   = blockIdx.x >> 3;
  const int tid = threadIdx.x;
  const int lane = tid & 63;
  const int p    = tid >> 6;        // wave index = M-tile index (batch/16)
  const int bb   = tid & 63;

  __shared__ __align__(16) _Float16 wlds[64 * NR * 8]; // [kc 0..63][n 0..31][8]
  __shared__ float  glds[BB * 33];                     // padded
  __shared__ float  blds[NR];
  __shared__ float  tlds[23 * NR];

  // ---- one-time init: gather this WG's 32 gate rows into LDS as fp16 ----
  for (int idx = tid; idx < 64 * NR; idx += 256) {
    int kc = idx >> 5;          // 0..31 input half, 32..63 recurrent half
    int n  = idx & 31;
    int g = n >> 3, jl = n & 7;
    int gr = g * 256 + w * HPW + jl;
    float v[8];
    if (kc < 32) {
      if (l == 0) { for (int j = 0; j < 8; ++j) v[j] = 0.f; }
      else {
        const float* src = Wih_rest + ((size_t)(l - 1) * G4 + gr) * HH + kc * 8;
        for (int j = 0; j < 8; ++j) v[j] = src[j];
      }
    } else {
      const float* src = Whh + ((size_t)l * G4 + gr) * HH + (kc - 32) * 8;
      for (int j = 0; j < 8; ++j) v[j] = src[j];
    }
    _Float16* dst = wlds + (size_t)idx * 8;
    for (int j = 0; j < 8; ++j) dst[j] = (_Float16)v[j];
  }
  if (tid < NR) {
    int g = tid >> 3, jl = tid & 7;
    int gr = g * 256 + w * HPW + jl;
    blds[tid] = bih[l * G4 + gr] + bhh[l * G4 + gr];
  }
  if (l == 0) {
    for (int idx = tid; idx < 23 * NR; idx += 256) {
      int v = idx >> 5, n = idx & 31;
      int g = n >> 3, jl = n & 7;
      tlds[idx] = xg0t[v * G4 + g * 256 + w * HPW + jl];
    }
  }
  __syncthreads();

  float c0 = 0.f, c1 = 0.f;

  const int arow = p * 16 + (lane & 15);  // A-fragment batch row
  const int kq   = lane >> 4;             // quarter-wave -> k chunk within tile
  const int n0   = lane & 15;             // B-fragment col (tile 0)
  const int n1   = 16 + n0;               // B-fragment col (tile 1)

  const _Float16* hin  = hseq + (size_t)(l > 0 ? l - 1 : 0) * LSTRIDE;
  _Float16*       hrec = hseq + (size_t)l * LSTRIDE;

  for (int t = 0; t < TT; ++t) {
    // ---- parallel polls: wave3 = own layer step t-1, wave2 = layer below step t ----
    if (t > 0 && p == 3) {
      const int* f = cnt + l * NW;
      for (;;) {
        int v = ldflag_x(f + (lane & 31));
        if (__all(v >= t)) break;
        __builtin_amdgcn_s_sleep(1);
      }
    }
    if (l > 0 && p == 2) {
      const int* f = cnt + (l - 1) * NW;
      for (;;) {
        int v = ldflag_x(f + (lane & 31));
        if (__all(v >= t + 1)) break;
        __builtin_amdgcn_s_sleep(1);
      }
    }
    __syncthreads();   // barrier A

    // ---- issue ALL loads (input half + recurrent half), one wait ----
    half8 aA[8], aB[8];
    if (l > 0) {
      const _Float16* ain = hin + (size_t)t * TSTRIDE;
#pragma unroll
      for (int kt = 0; kt < 8; ++kt) {
        int kc = kt * 4 + kq;
        gload8_x(aA[kt], ain + ((size_t)(kc * 64 + arow) << 3));
      }
    }
    if (t > 0) {
      const _Float16* ain = hrec + (size_t)(t - 1) * TSTRIDE;
#pragma unroll
      for (int kt = 0; kt < 8; ++kt) {
        int kc = kt * 4 + kq;
        gload8_x(aB[kt], ain + ((size_t)(kc * 64 + arow) << 3));
      }
    }
    wait_vm0();

    floatx4 acc0 = {0.f, 0.f, 0.f, 0.f};
    floatx4 acc1 = {0.f, 0.f, 0.f, 0.f};
    if (l > 0) {
#pragma unroll
      for (int kt = 0; kt < 8; ++kt) {
        int kc = kt * 4 + kq;
        half8 w0 = *(const half8*)(wlds + ((kc * 32 + n0) << 3));
        half8 w1 = *(const half8*)(wlds + ((kc * 32 + n1) << 3));
        acc0 = __builtin_amdgcn_mfma_f32_16x16x32_f16(aA[kt], w0, acc0, 0, 0, 0);
        acc1 = __builtin_amdgcn_mfma_f32_16x16x32_f16(aA[kt], w1, acc1, 0, 0, 0);
      }
    }
    if (t > 0) {
#pragma unroll
      for (int kt = 0; kt < 8; ++kt) {
        int kc = kt * 4 + kq;
        half8 w0 = *(const half8*)(wlds + (((32 + kc) * 32 + n0) << 3));
        half8 w1 = *(const half8*)(wlds + (((32 + kc) * 32 + n1) << 3));
        acc0 = __builtin_amdgcn_mfma_f32_16x16x32_f16(aB[kt], w0, acc0, 0, 0, 0);
        acc1 = __builtin_amdgcn_mfma_f32_16x16x32_f16(aB[kt], w1, acc1, 0, 0, 0);
      }
    }

    // ---- gates to LDS (C layout: col=lane&15, row=quad*4+reg) ----
    {
      int rbase = p * 16 + kq * 4;
#pragma unroll
      for (int r = 0; r < 4; ++r) {
        glds[(rbase + r) * 33 + n0]      = acc0[r];
        glds[(rbase + r) * 33 + 16 + n0] = acc1[r];
      }
    }
    __syncthreads();   // barrier B

    // ---- cell update: thread handles (bb, 2p) and (bb, 2p+1) ----
    union { _Float16 h[2]; int d; } hu;
    {
      int xv = 0;
      if (l == 0) xv = x[bb * TT + t];
#pragma unroll
      for (int q = 0; q < 2; ++q) {
        int j = 2 * p + q;
        float gi = glds[bb * 33 + j]      + blds[j];
        float gf = glds[bb * 33 + 8 + j]  + blds[8 + j];
        float gg = glds[bb * 33 + 16 + j] + blds[16 + j];
        float go = glds[bb * 33 + 24 + j] + blds[24 + j];
        if (l == 0) {
          const float* tb = tlds + xv * NR;
          gi += tb[j]; gf += tb[8 + j]; gg += tb[16 + j]; go += tb[24 + j];
        }
        float iv = sigm(gi), fv = sigm(gf), gv = tanh_f(gg), ov = sigm(go);
        float cv = (q == 0) ? c0 : c1;
        cv = fv * cv + iv * gv;
        float hv = ov * tanh_f(cv);
        if (q == 0) c0 = cv; else c1 = cv;
        hu.h[q] = (_Float16)hv;
      }
    }

    // ---- publish directly from registers: each thread one packed dword ----
    // element offset (w*64+bb)*8 + 2p  ->  int offset (w*64+bb)*4 + p
    stdword_x((int*)(hrec + (size_t)t * TSTRIDE) + ((w * 64 + bb) << 2) + p, hu.d);
    wait_vm0();        // this wave's h dwords are at the coherence point
    __syncthreads();   // barrier C: ALL waves' h stores are at the coherence point
    if (tid == 0)
      stdword_x(cnt + l * NW + w, t + 1);   // release: counter after data
  }
}

// ---------------------------------------------------------------------------
// Final projection: out[b][t][v] = h7[b][t][:] . fc_w[v][:] + fc_b[v]
__global__ __launch_bounds__(256) void fc_kernel(
    const _Float16* __restrict__ hseq7,  // [T][32][64][8] fp16
    const float* __restrict__ fcw,       // [23][256]
    const float* __restrict__ fcb,       // [23]
    float* __restrict__ out)             // [64][512][23]
{
  const int t = blockIdx.x;
  const int tid = threadIdx.x;
  __shared__ __align__(16) _Float16 hbuf[32 * 64 * 8];
  __shared__ float wbuf[23 * 256];
  __shared__ float bbuf[24];

  const _Float16* src = hseq7 + (size_t)t * TSTRIDE;
  for (int i = tid; i < 32 * 64; i += 256)
    ((half8*)hbuf)[i] = ((const half8*)src)[i];
  for (int i = tid; i < 23 * 256; i += 256) wbuf[i] = fcw[i];
  if (tid < 23) bbuf[tid] = fcb[tid];
  __syncthreads();

  for (int o = tid; o < 64 * 23; o += 256) {
    int b = o / 23, v = o - b * 23;
    float acc = bbuf[v];
#pragma unroll 4
    for (int kc = 0; kc < 32; ++kc) {
      half8 hv = *(const half8*)(hbuf + ((kc * 64 + b) << 3));
      const float* wr = wbuf + v * 256 + kc * 8;
#pragma unroll
      for (int j = 0; j < 8; ++j) acc += (float)hv[j] * wr[j];
    }
    out[((size_t)b * TT + t) * 23 + v] = acc;
  }
}

// ---------------------------------------------------------------------------
extern "C" void kernel_launch(void* const* d_in, const int* in_sizes, int n_in,
                              void* d_out, int out_size, void* d_ws, size_t ws_size,
                              hipStream_t stream) {
  const int*   x        = (const int*)d_in[0];
  const float* emb      = (const float*)d_in[1];
  const float* Wih0     = (const float*)d_in[2];
  const float* Wih_rest = (const float*)d_in[3];
  const float* Whh      = (const float*)d_in[4];
  const float* bihp     = (const float*)d_in[5];
  const float* bhhp     = (const float*)d_in[6];
  const float* fcw      = (const float*)d_in[7];
  const float* fcb      = (const float*)d_in[8];
  float* out = (float*)d_out;

  char* ws = (char*)d_ws;
  // ws layout (identical footprint to proven round-2): cnt 1KB | table @16384 | hseq @131072 (128MB)
  int*      cnt   = (int*)ws;                          // NL*NW*4 = 1024 B
  float*    table = (float*)(ws + 16384);              // 23*1024*4 = 94208 B
  _Float16* hseq  = (_Float16*)(ws + 131072);          // 8 * 16 MB

  hipMemsetAsync(ws, 0, 16384, stream);  // counters
  build_xg0<<<(23 * G4 + 255) / 256, 256, 0, stream>>>(emb, Wih0, table);
  lstm_pipeline<<<NL * NW, 256, 0, stream>>>(x, Wih_rest, Whh, bihp, bhhp, table, hseq, cnt);
  fc_kernel<<<TT, 256, 0, stream>>>(hseq + (size_t)7 * LSTRIDE, fcw, fcb, out);
}

// Round 5
// 2013.541 us; speedup vs baseline: 1.0270x; 1.0270x over previous
//
#include <hip/hip_runtime.h>
#include <cstdint>
#include <cstddef>

// Problem constants
#define BB   64     // batch
#define TT   512    // time steps
#define HH   256    // hidden
#define G4   1024   // 4*H
#define NL   8      // layers
#define NW   32     // workgroups per layer (hidden-unit slices)
#define HPW  8      // hidden units per WG
#define NR   32     // gate rows per WG (4 gates * HPW)

typedef _Float16 half8 __attribute__((ext_vector_type(8)));
typedef float   floatx4 __attribute__((ext_vector_type(4)));

__device__ __forceinline__ float sigm(float v)   { return 1.0f / (1.0f + __expf(-v)); }
__device__ __forceinline__ float tanh_f(float v) { return 1.0f - 2.0f / (__expf(2.0f * v) + 1.0f); }

// ---- coherent access helpers (bypass L1+L2, served at IF$ coherence point) ----
__device__ __forceinline__ void gload8_x(half8& d, const _Float16* p) {
  asm volatile("global_load_dwordx4 %0, %1, off sc0 sc1" : "=v"(d) : "v"(p) : "memory");
}
__device__ __forceinline__ void gstore8_x(_Float16* p, half8 d) {
  asm volatile("global_store_dwordx4 %0, %1, off sc0 sc1" :: "v"(p), "v"(d) : "memory");
}
__device__ __forceinline__ void stdword_x(int* p, int v) {
  asm volatile("global_store_dword %0, %1, off sc0 sc1" :: "v"(p), "v"(v) : "memory");
}
__device__ __forceinline__ void wait_vm0() {
  asm volatile("s_waitcnt vmcnt(0)" ::: "memory");
}
__device__ __forceinline__ int ldflag_x(const int* p) {
  int v; asm volatile("global_load_dword %0, %1, off sc0 sc1" : "=v"(v) : "v"(p) : "memory");
  wait_vm0(); return v;
}

// hseq layout per layer: [t][kblk=H/8=32][b=64][8] fp16 (MFMA A-fragment friendly)
#define TSTRIDE ((size_t)32 * BB * 8)         // 16384 elems per t
#define LSTRIDE ((size_t)TT * TSTRIDE)        // 8,388,608 elems per layer (16 MB)

// ---------------------------------------------------------------------------
// xg0 table: table[v][n] = sum_e emb[v][e] * Wih0[n][e]   (biases NOT included)
__global__ void build_xg0(const float* __restrict__ emb, const float* __restrict__ Wih0,
                          float* __restrict__ table) {
  int i = blockIdx.x * 256 + threadIdx.x;
  if (i >= 23 * G4) return;
  int v = i >> 10, n = i & (G4 - 1);
  float a = 0.f;
#pragma unroll
  for (int e = 0; e < 16; ++e) a += emb[v * 16 + e] * Wih0[n * 16 + e];
  table[i] = a;
}

// ---------------------------------------------------------------------------
// Persistent pipelined LSTM. grid = 256 blocks (NL layers x NW slices), 256 thr.
// Per step critical chain: publish-ack + counter-poll + h-load (3 coherence-point
// round trips) + MFMA + cell.  Design points:
//  - parallel polls: wave3 polls own-layer counters, wave2 polls layer-below
//  - per-slice MONOTONIC counters (cnt[l][w] = steps published): no atomics,
//    no reset, 32 contiguous dwords polled by 32 lanes + __all
//  - all 16 A+B fragment loads issued together under one vmcnt(0): the two
//    IF$ round trips overlap
//  - publish: h staged in LDS, wave0 stores the slice as 64x16B CONTIGUOUS
//    (round-4 lesson: scattered 4B coherent stores amplify WRITE_SIZE 4x),
//    waits only on ITS OWN stores, then releases the counter -- no barrier
//    on the release path; waves 1-3 run ahead to the next polls.
__global__ __launch_bounds__(256, 1) void lstm_pipeline(
    const int*   __restrict__ x,         // [B][T]
    const float* __restrict__ Wih_rest,  // [7][1024][256]
    const float* __restrict__ Whh,       // [8][1024][256]
    const float* __restrict__ bih,       // [8][1024]
    const float* __restrict__ bhh,       // [8][1024]
    const float* __restrict__ xg0t,      // [23][1024]
    _Float16* __restrict__ hseq,         // NL * LSTRIDE fp16
    int* __restrict__ cnt)               // [NL][NW] monotonic step counters
{
  const int l   = blockIdx.x & 7;
  const int w   = blockIdx.x >> 3;
  const int tid = threadIdx.x;
  const int lane = tid & 63;
  const int p    = tid >> 6;        // wave index = M-tile index (batch/16)
  const int bb   = tid & 63;

  __shared__ __align__(16) _Float16 wlds[64 * NR * 8]; // [kc 0..63][n 0..31][8]
  __shared__ float  glds[BB * 33];                     // padded
  __shared__ __align__(16) _Float16 hl[BB * 8];        // h staging for publish
  __shared__ float  blds[NR];
  __shared__ float  tlds[23 * NR];

  // ---- one-time init: gather this WG's 32 gate rows into LDS as fp16 ----
  for (int idx = tid; idx < 64 * NR; idx += 256) {
    int kc = idx >> 5;          // 0..31 input half, 32..63 recurrent half
    int n  = idx & 31;
    int g = n >> 3, jl = n & 7;
    int gr = g * 256 + w * HPW + jl;
    float v[8];
    if (kc < 32) {
      if (l == 0) { for (int j = 0; j < 8; ++j) v[j] = 0.f; }
      else {
        const float* src = Wih_rest + ((size_t)(l - 1) * G4 + gr) * HH + kc * 8;
        for (int j = 0; j < 8; ++j) v[j] = src[j];
      }
    } else {
      const float* src = Whh + ((size_t)l * G4 + gr) * HH + (kc - 32) * 8;
      for (int j = 0; j < 8; ++j) v[j] = src[j];
    }
    _Float16* dst = wlds + (size_t)idx * 8;
    for (int j = 0; j < 8; ++j) dst[j] = (_Float16)v[j];
  }
  if (tid < NR) {
    int g = tid >> 3, jl = tid & 7;
    int gr = g * 256 + w * HPW + jl;
    blds[tid] = bih[l * G4 + gr] + bhh[l * G4 + gr];
  }
  if (l == 0) {
    for (int idx = tid; idx < 23 * NR; idx += 256) {
      int v = idx >> 5, n = idx & 31;
      int g = n >> 3, jl = n & 7;
      tlds[idx] = xg0t[v * G4 + g * 256 + w * HPW + jl];
    }
  }
  __syncthreads();

  float c0 = 0.f, c1 = 0.f;

  const int arow = p * 16 + (lane & 15);  // A-fragment batch row
  const int kq   = lane >> 4;             // quarter-wave -> k chunk within tile
  const int n0   = lane & 15;             // B-fragment col (tile 0)
  const int n1   = 16 + n0;               // B-fragment col (tile 1)

  const _Float16* hin  = hseq + (size_t)(l > 0 ? l - 1 : 0) * LSTRIDE;
  _Float16*       hrec = hseq + (size_t)l * LSTRIDE;

  for (int t = 0; t < TT; ++t) {
    // ---- parallel polls: wave3 = own layer step t-1, wave2 = layer below step t ----
    if (t > 0 && p == 3) {
      const int* f = cnt + l * NW;
      for (;;) {
        int v = ldflag_x(f + (lane & 31));
        if (__all(v >= t)) break;
        __builtin_amdgcn_s_sleep(1);
      }
    }
    if (l > 0 && p == 2) {
      const int* f = cnt + (l - 1) * NW;
      for (;;) {
        int v = ldflag_x(f + (lane & 31));
        if (__all(v >= t + 1)) break;
        __builtin_amdgcn_s_sleep(1);
      }
    }
    __syncthreads();   // barrier A

    // ---- issue ALL loads (input half + recurrent half), one wait ----
    half8 aA[8], aB[8];
    if (l > 0) {
      const _Float16* ain = hin + (size_t)t * TSTRIDE;
#pragma unroll
      for (int kt = 0; kt < 8; ++kt) {
        int kc = kt * 4 + kq;
        gload8_x(aA[kt], ain + ((size_t)(kc * 64 + arow) << 3));
      }
    }
    if (t > 0) {
      const _Float16* ain = hrec + (size_t)(t - 1) * TSTRIDE;
#pragma unroll
      for (int kt = 0; kt < 8; ++kt) {
        int kc = kt * 4 + kq;
        gload8_x(aB[kt], ain + ((size_t)(kc * 64 + arow) << 3));
      }
    }
    wait_vm0();

    floatx4 acc0 = {0.f, 0.f, 0.f, 0.f};
    floatx4 acc1 = {0.f, 0.f, 0.f, 0.f};
    if (l > 0) {
#pragma unroll
      for (int kt = 0; kt < 8; ++kt) {
        int kc = kt * 4 + kq;
        half8 w0 = *(const half8*)(wlds + ((kc * 32 + n0) << 3));
        half8 w1 = *(const half8*)(wlds + ((kc * 32 + n1) << 3));
        acc0 = __builtin_amdgcn_mfma_f32_16x16x32_f16(aA[kt], w0, acc0, 0, 0, 0);
        acc1 = __builtin_amdgcn_mfma_f32_16x16x32_f16(aA[kt], w1, acc1, 0, 0, 0);
      }
    }
    if (t > 0) {
#pragma unroll
      for (int kt = 0; kt < 8; ++kt) {
        int kc = kt * 4 + kq;
        half8 w0 = *(const half8*)(wlds + (((32 + kc) * 32 + n0) << 3));
        half8 w1 = *(const half8*)(wlds + (((32 + kc) * 32 + n1) << 3));
        acc0 = __builtin_amdgcn_mfma_f32_16x16x32_f16(aB[kt], w0, acc0, 0, 0, 0);
        acc1 = __builtin_amdgcn_mfma_f32_16x16x32_f16(aB[kt], w1, acc1, 0, 0, 0);
      }
    }

    // ---- gates to LDS (C layout: col=lane&15, row=quad*4+reg) ----
    {
      int rbase = p * 16 + kq * 4;
#pragma unroll
      for (int r = 0; r < 4; ++r) {
        glds[(rbase + r) * 33 + n0]      = acc0[r];
        glds[(rbase + r) * 33 + 16 + n0] = acc1[r];
      }
    }
    __syncthreads();   // barrier B

    // ---- cell update: thread handles (bb, 2p) and (bb, 2p+1) ----
    {
      int xv = 0;
      if (l == 0) xv = x[bb * TT + t];
      float h0, h1;
#pragma unroll
      for (int q = 0; q < 2; ++q) {
        int j = 2 * p + q;
        float gi = glds[bb * 33 + j]      + blds[j];
        float gf = glds[bb * 33 + 8 + j]  + blds[8 + j];
        float gg = glds[bb * 33 + 16 + j] + blds[16 + j];
        float go = glds[bb * 33 + 24 + j] + blds[24 + j];
        if (l == 0) {
          const float* tb = tlds + xv * NR;
          gi += tb[j]; gf += tb[8 + j]; gg += tb[16 + j]; go += tb[24 + j];
        }
        float iv = sigm(gi), fv = sigm(gf), gv = tanh_f(gg), ov = sigm(go);
        float cv = (q == 0) ? c0 : c1;
        cv = fv * cv + iv * gv;
        float hv = ov * tanh_f(cv);
        if (q == 0) { c0 = cv; h0 = hv; } else { c1 = cv; h1 = hv; }
      }
      hl[bb * 8 + 2 * p]     = (_Float16)h0;
      hl[bb * 8 + 2 * p + 1] = (_Float16)h1;
    }
    __syncthreads();   // barrier C: hl complete

    // ---- publish: wave0 stores the whole 1KB slice contiguously, then
    //      releases the counter after waiting on ITS OWN stores only.
    //      Waves 1-3 run ahead to the next loop-top polls. ----
    if (tid < 64) {
      half8 hv = *(const half8*)(hl + tid * 8);
      gstore8_x(hrec + (size_t)t * TSTRIDE + ((size_t)w * 64 + tid) * 8, hv);
      wait_vm0();      // wave0's h stores are at the coherence point
      if (tid == 0)
        stdword_x(cnt + l * NW + w, t + 1);   // release
    }
    // next iteration's barrier A closes the step
  }
}

// ---------------------------------------------------------------------------
// Final projection: out[b][t][v] = h7[b][t][:] . fc_w[v][:] + fc_b[v]
__global__ __launch_bounds__(256) void fc_kernel(
    const _Float16* __restrict__ hseq7,  // [T][32][64][8] fp16
    const float* __restrict__ fcw,       // [23][256]
    const float* __restrict__ fcb,       // [23]
    float* __restrict__ out)             // [64][512][23]
{
  const int t = blockIdx.x;
  const int tid = threadIdx.x;
  __shared__ __align__(16) _Float16 hbuf[32 * 64 * 8];
  __shared__ float wbuf[23 * 256];
  __shared__ float bbuf[24];

  const _Float16* src = hseq7 + (size_t)t * TSTRIDE;
  for (int i = tid; i < 32 * 64; i += 256)
    ((half8*)hbuf)[i] = ((const half8*)src)[i];
  for (int i = tid; i < 23 * 256; i += 256) wbuf[i] = fcw[i];
  if (tid < 23) bbuf[tid] = fcb[tid];
  __syncthreads();

  for (int o = tid; o < 64 * 23; o += 256) {
    int b = o / 23, v = o - b * 23;
    float acc = bbuf[v];
#pragma unroll 4
    for (int kc = 0; kc < 32; ++kc) {
      half8 hv = *(const half8*)(hbuf + ((kc * 64 + b) << 3));
      const float* wr = wbuf + v * 256 + kc * 8;
#pragma unroll
      for (int j = 0; j < 8; ++j) acc += (float)hv[j] * wr[j];
    }
    out[((size_t)b * TT + t) * 23 + v] = acc;
  }
}

// ---------------------------------------------------------------------------
extern "C" void kernel_launch(void* const* d_in, const int* in_sizes, int n_in,
                              void* d_out, int out_size, void* d_ws, size_t ws_size,
                              hipStream_t stream) {
  const int*   x        = (const int*)d_in[0];
  const float* emb      = (const float*)d_in[1];
  const float* Wih0     = (const float*)d_in[2];
  const float* Wih_rest = (const float*)d_in[3];
  const float* Whh      = (const float*)d_in[4];
  const float* bihp     = (const float*)d_in[5];
  const float* bhhp     = (const float*)d_in[6];
  const float* fcw      = (const float*)d_in[7];
  const float* fcb      = (const float*)d_in[8];
  float* out = (float*)d_out;

  char* ws = (char*)d_ws;
  // ws layout (identical footprint to proven round-2): cnt 1KB | table @16384 | hseq @131072 (128MB)
  int*      cnt   = (int*)ws;                          // NL*NW*4 = 1024 B
  float*    table = (float*)(ws + 16384);              // 23*1024*4 = 94208 B
  _Float16* hseq  = (_Float16*)(ws + 131072);          // 8 * 16 MB

  hipMemsetAsync(ws, 0, 16384, stream);  // counters
  build_xg0<<<(23 * G4 + 255) / 256, 256, 0, stream>>>(emb, Wih0, table);
  lstm_pipeline<<<NL * NW, 256, 0, stream>>>(x, Wih_rest, Whh, bihp, bhhp, table, hseq, cnt);
  fc_kernel<<<TT, 256, 0, stream>>>(hseq + (size_t)7 * LSTRIDE, fcw, fcb, out);
}

// Round 7
// 1908.655 us; speedup vs baseline: 1.0835x; 1.0550x over previous
//
#include <hip/hip_runtime.h>
#include <cstdint>
#include <cstddef>

// Problem constants
#define BB   64     // batch
#define TT   512    // time steps
#define HH   256    // hidden
#define G4   1024   // 4*H
#define NL   8      // layers
#define NW   32     // workgroups per layer (hidden-unit slices)
#define HPW  8      // hidden units per WG
#define NR   32     // gate rows per WG (4 gates * HPW)

typedef _Float16 half8 __attribute__((ext_vector_type(8)));
typedef float   floatx4 __attribute__((ext_vector_type(4)));

__device__ __forceinline__ float sigm(float v)   { return 1.0f / (1.0f + __expf(-v)); }
__device__ __forceinline__ float tanh_f(float v) { return 1.0f - 2.0f / (__expf(2.0f * v) + 1.0f); }

// ---- coherent access helpers (sc0 sc1: bypass L1+L2, served at IF$) ----
// Used ONLY for h-publish stores and counter stores/polls. h READS are normal
// cached loads: safe because every h line is written exactly once and only
// read after the sc0sc1 counter poll confirms the release (no pre-touch), and
// kernel-dispatch start invalidates stale/poison lines. Cached reads let the
// 64 consumer WGs of each h-set share per-XCD L2 fills instead of 64 separate
// IF$ round trips -- attacks the coherent-path congestion that R2-R5 scheduling
// changes couldn't move.
__device__ __forceinline__ void gstore8_x(_Float16* p, half8 d) {
  asm volatile("global_store_dwordx4 %0, %1, off sc0 sc1" :: "v"(p), "v"(d) : "memory");
}
__device__ __forceinline__ void stdword_x(int* p, int v) {
  asm volatile("global_store_dword %0, %1, off sc0 sc1" :: "v"(p), "v"(v) : "memory");
}
__device__ __forceinline__ void wait_vm0() {
  asm volatile("s_waitcnt vmcnt(0)" ::: "memory");
}
__device__ __forceinline__ int ldflag_x(const int* p) {
  int v; asm volatile("global_load_dword %0, %1, off sc0 sc1" : "=v"(v) : "v"(p) : "memory");
  wait_vm0(); return v;
}

// hseq layout per layer: [t][kblk=H/8=32][b=64][8] fp16 (MFMA A-fragment friendly)
#define TSTRIDE ((size_t)32 * BB * 8)         // 16384 elems per t
#define LSTRIDE ((size_t)TT * TSTRIDE)        // 8,388,608 elems per layer (16 MB)

// ---------------------------------------------------------------------------
// xg0 table: table[v][n] = sum_e emb[v][e] * Wih0[n][e]   (biases NOT included)
__global__ void build_xg0(const float* __restrict__ emb, const float* __restrict__ Wih0,
                          float* __restrict__ table) {
  int i = blockIdx.x * 256 + threadIdx.x;
  if (i >= 23 * G4) return;
  int v = i >> 10, n = i & (G4 - 1);
  float a = 0.f;
#pragma unroll
  for (int e = 0; e < 16; ++e) a += emb[v * 16 + e] * Wih0[n * 16 + e];
  table[i] = a;
}

// ---------------------------------------------------------------------------
// Persistent pipelined LSTM. grid = 256 blocks (NL layers x NW slices), 256 thr.
// Identical to the proven round-5 structure EXCEPT: h fragment loads are
// normal cached loads (L1/L2 path) instead of sc0sc1 coherent loads.
__global__ __launch_bounds__(256, 1) void lstm_pipeline(
    const int*   __restrict__ x,         // [B][T]
    const float* __restrict__ Wih_rest,  // [7][1024][256]
    const float* __restrict__ Whh,       // [8][1024][256]
    const float* __restrict__ bih,       // [8][1024]
    const float* __restrict__ bhh,       // [8][1024]
    const float* __restrict__ xg0t,      // [23][1024]
    _Float16* __restrict__ hseq,         // NL * LSTRIDE fp16
    int* __restrict__ cnt)               // [NL][NW] monotonic step counters
{
  const int l   = blockIdx.x & 7;
  const int w   = blockIdx.x >> 3;
  const int tid = threadIdx.x;
  const int lane = tid & 63;
  const int p    = tid >> 6;        // wave index = M-tile index (batch/16)
  const int bb   = tid & 63;

  __shared__ __align__(16) _Float16 wlds[64 * NR * 8]; // [kc 0..63][n 0..31][8]
  __shared__ float  glds[BB * 33];                     // padded
  __shared__ __align__(16) _Float16 hl[BB * 8];        // h staging for publish
  __shared__ float  blds[NR];
  __shared__ float  tlds[23 * NR];

  // ---- one-time init: gather this WG's 32 gate rows into LDS as fp16 ----
  for (int idx = tid; idx < 64 * NR; idx += 256) {
    int kc = idx >> 5;          // 0..31 input half, 32..63 recurrent half
    int n  = idx & 31;
    int g = n >> 3, jl = n & 7;
    int gr = g * 256 + w * HPW + jl;
    float v[8];
    if (kc < 32) {
      if (l == 0) { for (int j = 0; j < 8; ++j) v[j] = 0.f; }
      else {
        const float* src = Wih_rest + ((size_t)(l - 1) * G4 + gr) * HH + kc * 8;
        for (int j = 0; j < 8; ++j) v[j] = src[j];
      }
    } else {
      const float* src = Whh + ((size_t)l * G4 + gr) * HH + (kc - 32) * 8;
      for (int j = 0; j < 8; ++j) v[j] = src[j];
    }
    _Float16* dst = wlds + (size_t)idx * 8;
    for (int j = 0; j < 8; ++j) dst[j] = (_Float16)v[j];
  }
  if (tid < NR) {
    int g = tid >> 3, jl = tid & 7;
    int gr = g * 256 + w * HPW + jl;
    blds[tid] = bih[l * G4 + gr] + bhh[l * G4 + gr];
  }
  if (l == 0) {
    for (int idx = tid; idx < 23 * NR; idx += 256) {
      int v = idx >> 5, n = idx & 31;
      int g = n >> 3, jl = n & 7;
      tlds[idx] = xg0t[v * G4 + g * 256 + w * HPW + jl];
    }
  }
  // Belt-and-braces: agent-scope acquire -> invalidate any stale L1/L2 lines
  // (harness poison) before any cached h reads. Dispatch start does this
  // implicitly too.
  if (tid == 0) (void)__hip_atomic_load(cnt, __ATOMIC_ACQUIRE, __HIP_MEMORY_SCOPE_AGENT);
  __syncthreads();

  float c0 = 0.f, c1 = 0.f;

  const int arow = p * 16 + (lane & 15);  // A-fragment batch row
  const int kq   = lane >> 4;             // quarter-wave -> k chunk within tile
  const int n0   = lane & 15;             // B-fragment col (tile 0)
  const int n1   = 16 + n0;               // B-fragment col (tile 1)

  const _Float16* hin  = hseq + (size_t)(l > 0 ? l - 1 : 0) * LSTRIDE;
  _Float16*       hrec = hseq + (size_t)l * LSTRIDE;

  for (int t = 0; t < TT; ++t) {
    // ---- parallel polls: wave3 = own layer step t-1, wave2 = layer below step t ----
    if (t > 0 && p == 3) {
      const int* f = cnt + l * NW;
      for (;;) {
        int v = ldflag_x(f + (lane & 31));
        if (__all(v >= t)) break;
        __builtin_amdgcn_s_sleep(1);
      }
    }
    if (l > 0 && p == 2) {
      const int* f = cnt + (l - 1) * NW;
      for (;;) {
        int v = ldflag_x(f + (lane & 31));
        if (__all(v >= t + 1)) break;
        __builtin_amdgcn_s_sleep(1);
      }
    }
    __syncthreads();   // barrier A

    // ---- issue ALL loads (input half + recurrent half) via the CACHED path ----
    half8 aA[8], aB[8];
    if (l > 0) {
      const _Float16* ain = hin + (size_t)t * TSTRIDE;
#pragma unroll
      for (int kt = 0; kt < 8; ++kt) {
        int kc = kt * 4 + kq;
        aA[kt] = *(const half8*)(ain + ((size_t)(kc * 64 + arow) << 3));
      }
    }
    if (t > 0) {
      const _Float16* ain = hrec + (size_t)(t - 1) * TSTRIDE;
#pragma unroll
      for (int kt = 0; kt < 8; ++kt) {
        int kc = kt * 4 + kq;
        aB[kt] = *(const half8*)(ain + ((size_t)(kc * 64 + arow) << 3));
      }
    }

    floatx4 acc0 = {0.f, 0.f, 0.f, 0.f};
    floatx4 acc1 = {0.f, 0.f, 0.f, 0.f};
    if (l > 0) {
#pragma unroll
      for (int kt = 0; kt < 8; ++kt) {
        int kc = kt * 4 + kq;
        half8 w0 = *(const half8*)(wlds + ((kc * 32 + n0) << 3));
        half8 w1 = *(const half8*)(wlds + ((kc * 32 + n1) << 3));
        acc0 = __builtin_amdgcn_mfma_f32_16x16x32_f16(aA[kt], w0, acc0, 0, 0, 0);
        acc1 = __builtin_amdgcn_mfma_f32_16x16x32_f16(aA[kt], w1, acc1, 0, 0, 0);
      }
    }
    if (t > 0) {
#pragma unroll
      for (int kt = 0; kt < 8; ++kt) {
        int kc = kt * 4 + kq;
        half8 w0 = *(const half8*)(wlds + (((32 + kc) * 32 + n0) << 3));
        half8 w1 = *(const half8*)(wlds + (((32 + kc) * 32 + n1) << 3));
        acc0 = __builtin_amdgcn_mfma_f32_16x16x32_f16(aB[kt], w0, acc0, 0, 0, 0);
        acc1 = __builtin_amdgcn_mfma_f32_16x16x32_f16(aB[kt], w1, acc1, 0, 0, 0);
      }
    }

    // ---- gates to LDS (C layout: col=lane&15, row=quad*4+reg) ----
    {
      int rbase = p * 16 + kq * 4;
#pragma unroll
      for (int r = 0; r < 4; ++r) {
        glds[(rbase + r) * 33 + n0]      = acc0[r];
        glds[(rbase + r) * 33 + 16 + n0] = acc1[r];
      }
    }
    __syncthreads();   // barrier B

    // ---- cell update: thread handles (bb, 2p) and (bb, 2p+1) ----
    {
      int xv = 0;
      if (l == 0) xv = x[bb * TT + t];
      float h0, h1;
#pragma unroll
      for (int q = 0; q < 2; ++q) {
        int j = 2 * p + q;
        float gi = glds[bb * 33 + j]      + blds[j];
        float gf = glds[bb * 33 + 8 + j]  + blds[8 + j];
        float gg = glds[bb * 33 + 16 + j] + blds[16 + j];
        float go = glds[bb * 33 + 24 + j] + blds[24 + j];
        if (l == 0) {
          const float* tb = tlds + xv * NR;
          gi += tb[j]; gf += tb[8 + j]; gg += tb[16 + j]; go += tb[24 + j];
        }
        float iv = sigm(gi), fv = sigm(gf), gv = tanh_f(gg), ov = sigm(go);
        float cv = (q == 0) ? c0 : c1;
        cv = fv * cv + iv * gv;
        float hv = ov * tanh_f(cv);
        if (q == 0) { c0 = cv; h0 = hv; } else { c1 = cv; h1 = hv; }
      }
      hl[bb * 8 + 2 * p]     = (_Float16)h0;
      hl[bb * 8 + 2 * p + 1] = (_Float16)h1;
    }
    __syncthreads();   // barrier C: hl complete

    // ---- publish: wave0 stores the whole 1KB slice contiguously (sc0 sc1),
    //      waits on ITS OWN stores only, then releases the counter.
    //      Waves 1-3 run ahead to the next loop-top polls. ----
    if (tid < 64) {
      half8 hv = *(const half8*)(hl + tid * 8);
      gstore8_x(hrec + (size_t)t * TSTRIDE + ((size_t)w * 64 + tid) * 8, hv);
      wait_vm0();      // wave0's h stores are at the coherence point
      if (tid == 0)
        stdword_x(cnt + l * NW + w, t + 1);   // release
    }
    // next iteration's barrier A closes the step
  }
}

// ---------------------------------------------------------------------------
// Final projection: out[b][t][v] = h7[b][t][:] . fc_w[v][:] + fc_b[v]
__global__ __launch_bounds__(256) void fc_kernel(
    const _Float16* __restrict__ hseq7,  // [T][32][64][8] fp16
    const float* __restrict__ fcw,       // [23][256]
    const float* __restrict__ fcb,       // [23]
    float* __restrict__ out)             // [64][512][23]
{
  const int t = blockIdx.x;
  const int tid = threadIdx.x;
  __shared__ __align__(16) _Float16 hbuf[32 * 64 * 8];
  __shared__ float wbuf[23 * 256];
  __shared__ float bbuf[24];

  const _Float16* src = hseq7 + (size_t)t * TSTRIDE;
  for (int i = tid; i < 32 * 64; i += 256)
    ((half8*)hbuf)[i] = ((const half8*)src)[i];
  for (int i = tid; i < 23 * 256; i += 256) wbuf[i] = fcw[i];
  if (tid < 23) bbuf[tid] = fcb[tid];
  __syncthreads();

  for (int o = tid; o < 64 * 23; o += 256) {
    int b = o / 23, v = o - b * 23;
    float acc = bbuf[v];
#pragma unroll 4
    for (int kc = 0; kc < 32; ++kc) {
      half8 hv = *(const half8*)(hbuf + ((kc * 64 + b) << 3));
      const float* wr = wbuf + v * 256 + kc * 8;
#pragma unroll
      for (int j = 0; j < 8; ++j) acc += (float)hv[j] * wr[j];
    }
    out[((size_t)b * TT + t) * 23 + v] = acc;
  }
}

// ---------------------------------------------------------------------------
extern "C" void kernel_launch(void* const* d_in, const int* in_sizes, int n_in,
                              void* d_out, int out_size, void* d_ws, size_t ws_size,
                              hipStream_t stream) {
  const int*   x        = (const int*)d_in[0];
  const float* emb      = (const float*)d_in[1];
  const float* Wih0     = (const float*)d_in[2];
  const float* Wih_rest = (const float*)d_in[3];
  const float* Whh      = (const float*)d_in[4];
  const float* bihp     = (const float*)d_in[5];
  const float* bhhp     = (const float*)d_in[6];
  const float* fcw      = (const float*)d_in[7];
  const float* fcb      = (const float*)d_in[8];
  float* out = (float*)d_out;

  char* ws = (char*)d_ws;
  // ws layout (identical footprint to proven rounds 2/4/5):
  // cnt 1KB | table @16384 | hseq @131072 (128MB)
  int*      cnt   = (int*)ws;                          // NL*NW*4 = 1024 B
  float*    table = (float*)(ws + 16384);              // 23*1024*4 = 94208 B
  _Float16* hseq  = (_Float16*)(ws + 131072);          // 8 * 16 MB

  hipMemsetAsync(ws, 0, 16384, stream);  // counters
  build_xg0<<<(23 * G4 + 255) / 256, 256, 0, stream>>>(emb, Wih0, table);
  lstm_pipeline<<<NL * NW, 256, 0, stream>>>(x, Wih_rest, Whh, bihp, bhhp, table, hseq, cnt);
  fc_kernel<<<TT, 256, 0, stream>>>(hseq + (size_t)7 * LSTRIDE, fcw, fcb, out);
}